// Round 1
// baseline (1437.278 us; speedup 1.0000x reference)
//
#include <hip/hip_runtime.h>
#include <hip/hip_bf16.h>
#include <math.h>

#define T_SEQ 1024
#define NB 4
#define NH 16
#define DD 64
#define CC 1024
#define TQ 64   // q rows per block in attention
#define ST 32   // s-tile (key cols) per iteration
#define PW 95   // p-window rows = TQ + ST - 1

// ---------------------------------------------------------------------------
// Generic fp32 GEMM:  C[m,n] = sum_k A[m,k] * W[n,k] (+ bias[n])
// A: [M,K] row-major, W: [N,K] row-major (i.e. C = A @ W^T), N%64==0, K%16==0
// 64x64 tile, 256 threads, 4x4 micro-tile.
// ---------------------------------------------------------------------------
__global__ __launch_bounds__(256) void gemm_nt(
    const float* __restrict__ A, const float* __restrict__ W,
    const float* __restrict__ bias, float* __restrict__ C,
    int M, int N, int K)
{
  __shared__ __align__(16) float As[16][68];
  __shared__ __align__(16) float Ws[16][68];
  const int tid = threadIdx.x;
  const int lr = tid >> 2;          // 0..63 row within tile
  const int lk = (tid & 3) << 2;    // 0,4,8,12
  const int ty = tid >> 4, tx = tid & 15;
  const int bm = blockIdx.y * 64, bn = blockIdx.x * 64;
  float acc[4][4] = {{0.f, 0.f, 0.f, 0.f}, {0.f, 0.f, 0.f, 0.f},
                     {0.f, 0.f, 0.f, 0.f}, {0.f, 0.f, 0.f, 0.f}};
  const bool aval = (bm + lr) < M;
  const float* Arow = A + (size_t)(bm + lr) * K;
  const float* Wrow = W + (size_t)(bn + lr) * K;

  for (int k0 = 0; k0 < K; k0 += 16) {
    float4 a4 = make_float4(0.f, 0.f, 0.f, 0.f);
    if (aval) a4 = *(const float4*)(Arow + k0 + lk);
    const float4 w4 = *(const float4*)(Wrow + k0 + lk);
    As[lk + 0][lr] = a4.x; As[lk + 1][lr] = a4.y;
    As[lk + 2][lr] = a4.z; As[lk + 3][lr] = a4.w;
    Ws[lk + 0][lr] = w4.x; Ws[lk + 1][lr] = w4.y;
    Ws[lk + 2][lr] = w4.z; Ws[lk + 3][lr] = w4.w;
    __syncthreads();
#pragma unroll
    for (int kk = 0; kk < 16; ++kk) {
      const float4 av = *(const float4*)&As[kk][ty << 2];
      const float4 wv = *(const float4*)&Ws[kk][tx << 2];
      acc[0][0] += av.x * wv.x; acc[0][1] += av.x * wv.y;
      acc[0][2] += av.x * wv.z; acc[0][3] += av.x * wv.w;
      acc[1][0] += av.y * wv.x; acc[1][1] += av.y * wv.y;
      acc[1][2] += av.y * wv.z; acc[1][3] += av.y * wv.w;
      acc[2][0] += av.z * wv.x; acc[2][1] += av.z * wv.y;
      acc[2][2] += av.z * wv.z; acc[2][3] += av.z * wv.w;
      acc[3][0] += av.w * wv.x; acc[3][1] += av.w * wv.y;
      acc[3][2] += av.w * wv.z; acc[3][3] += av.w * wv.w;
    }
    __syncthreads();
  }

  float4 bb = make_float4(0.f, 0.f, 0.f, 0.f);
  if (bias) bb = *(const float4*)&bias[bn + (tx << 2)];
#pragma unroll
  for (int i = 0; i < 4; ++i) {
    const int m = bm + (ty << 2) + i;
    if (m < M) {
      float4 o;
      o.x = acc[i][0] + bb.x; o.y = acc[i][1] + bb.y;
      o.z = acc[i][2] + bb.z; o.w = acc[i][3] + bb.w;
      *(float4*)&C[(size_t)m * N + bn + (tx << 2)] = o;
    }
  }
}

// ---------------------------------------------------------------------------
// Precompute rank-1 bias dots:
//   uk[b*H*T + h*T + s]   = pos_bias_u[h,:] . k[b,s,h,:]
//   vp[idx*H + h]         = pos_bias_v[h,:] . p[idx,h,:]
// k stored [T,B,C] (row = s*B+b); p stored [2T-1, C].
// ---------------------------------------------------------------------------
__global__ __launch_bounds__(256) void precompute_kernel(
    const float* __restrict__ k, const float* __restrict__ p,
    const float* __restrict__ pbu, const float* __restrict__ pbv,
    float* __restrict__ uk, float* __restrict__ vp)
{
  const int i = blockIdx.x * 256 + threadIdx.x;
  const int NUK = NB * NH * T_SEQ;  // 65536
  if (i < NUK) {
    const int b = i >> 14, h = (i >> 10) & 15, s = i & 1023;
    const float4* kr = (const float4*)(k + ((size_t)s * NB + b) * CC + h * DD);
    const float4* ur = (const float4*)(pbu + h * DD);
    float sum = 0.f;
#pragma unroll
    for (int d4 = 0; d4 < 16; ++d4) {
      const float4 a = kr[d4], u4 = ur[d4];
      sum += a.x * u4.x + a.y * u4.y + a.z * u4.z + a.w * u4.w;
    }
    uk[i] = sum;
  } else if (i < NUK + (2 * T_SEQ - 1) * NH) {
    const int j = i - NUK;
    const int idx = j >> 4, h = j & 15;
    const float4* pr = (const float4*)(p + (size_t)idx * CC + h * DD);
    const float4* vr = (const float4*)(pbv + h * DD);
    float sum = 0.f;
#pragma unroll
    for (int d4 = 0; d4 < 16; ++d4) {
      const float4 a = pr[d4], v4 = vr[d4];
      sum += a.x * v4.x + a.y * v4.y + a.z * v4.z + a.w * v4.w;
    }
    vp[idx * NH + h] = sum;
  }
}

// ---------------------------------------------------------------------------
// Fused rel-pos attention, flash-style online softmax.
// score[t,s] = 0.125*( q[t].k[s] + q[t].p[s-t+T-1] + uk[s] + vp[s-t+T-1] )
// One block per (b, h, 64-row q-tile); iterate s in tiles of 32.
// x output stored [T,B,C].
// ---------------------------------------------------------------------------
__global__ __launch_bounds__(256) void attn_kernel(
    const float* __restrict__ q, const float* __restrict__ k,
    const float* __restrict__ v, const float* __restrict__ p,
    const float* __restrict__ uk, const float* __restrict__ vp,
    float* __restrict__ x)
{
  const int t0 = blockIdx.x * TQ;
  const int h  = blockIdx.y;
  const int b  = blockIdx.z;
  const int tid = threadIdx.x;

  __shared__ __align__(16) float qT[DD][69];    // [d][t], pitch 69 (bank spread)
  __shared__ __align__(16) float ksT[DD][36];   // [d][s]
  __shared__ __align__(16) float vs[ST][68];    // [s][d]
  __shared__ __align__(16) float psT[DD][97];   // [d][li], li = s-t-(s0-t0)+63
  __shared__ __align__(16) float Pm[TQ][37];    // probabilities [t][s]
  __shared__ float m_row[TQ], l_row[TQ], alpha_row[TQ];
  __shared__ float uk_t[ST];
  __shared__ float vp_w[PW + 1];

  const int ty = tid >> 4, tx = tid & 15;

  // load q tile transposed: qT[d][t] = q[b, t0+t, h, d]
#pragma unroll
  for (int j = 0; j < 4; ++j) {
    const int t = ty + j * 16;
    const float4 qv = *(const float4*)&q[((size_t)(t0 + t) * NB + b) * CC + h * DD + (tx << 2)];
    qT[(tx << 2) + 0][t] = qv.x; qT[(tx << 2) + 1][t] = qv.y;
    qT[(tx << 2) + 2][t] = qv.z; qT[(tx << 2) + 3][t] = qv.w;
  }
  if (tid < TQ) { m_row[tid] = -3.0e38f; l_row[tid] = 0.f; }

  float acc[4][4];
#pragma unroll
  for (int i = 0; i < 4; ++i)
#pragma unroll
    for (int j = 0; j < 4; ++j) acc[i][j] = 0.f;

  // score-phase ownership: rows tA..tA+1, cols sA..sA+3
  const int tyS = tid >> 3, txS = tid & 7;
  const int tA = tyS << 1, sA = txS << 2;

  for (int s0 = 0; s0 < T_SEQ; s0 += ST) {
    const int w0 = s0 - t0 + (T_SEQ - TQ);  // global p row of window li=0

    // ---- stage k, v, p-window, bias dots into LDS ----
#pragma unroll
    for (int j = 0; j < 2; ++j) {
      const int s = ty + j * 16;
      const float4 kv = *(const float4*)&k[((size_t)(s0 + s) * NB + b) * CC + h * DD + (tx << 2)];
      ksT[(tx << 2) + 0][s] = kv.x; ksT[(tx << 2) + 1][s] = kv.y;
      ksT[(tx << 2) + 2][s] = kv.z; ksT[(tx << 2) + 3][s] = kv.w;
      const float4 vv = *(const float4*)&v[((size_t)(s0 + s) * NB + b) * CC + h * DD + (tx << 2)];
      *(float4*)&vs[s][tx << 2] = vv;
    }
#pragma unroll
    for (int j = 0; j < 6; ++j) {
      const int li = ty + j * 16;
      if (li < PW) {
        const float4 pv = *(const float4*)&p[((size_t)(w0 + li)) * CC + h * DD + (tx << 2)];
        psT[(tx << 2) + 0][li] = pv.x; psT[(tx << 2) + 1][li] = pv.y;
        psT[(tx << 2) + 2][li] = pv.z; psT[(tx << 2) + 3][li] = pv.w;
      }
    }
    if (tid < ST) uk_t[tid] = uk[((size_t)b * NH + h) * T_SEQ + s0 + tid];
    if (tid < PW) vp_w[tid] = vp[(size_t)(w0 + tid) * NH + h];
    __syncthreads();

    // ---- scores: 2 rows x 4 cols per thread ----
    float sc[2][4] = {{0.f, 0.f, 0.f, 0.f}, {0.f, 0.f, 0.f, 0.f}};
    const int lb = sA - tA + 62;  // li for (it=1, js=0); it=0 uses lb+1+js
#pragma unroll 4
    for (int d = 0; d < DD; ++d) {
      const float q0 = qT[d][tA], q1 = qT[d][tA + 1];
      const float4 k4 = *(const float4*)&ksT[d][sA];
      const float p0 = psT[d][lb + 0], p1 = psT[d][lb + 1], p2 = psT[d][lb + 2],
                  p3 = psT[d][lb + 3], p4 = psT[d][lb + 4];
      sc[0][0] += q0 * k4.x; sc[0][1] += q0 * k4.y;
      sc[0][2] += q0 * k4.z; sc[0][3] += q0 * k4.w;
      sc[1][0] += q1 * k4.x; sc[1][1] += q1 * k4.y;
      sc[1][2] += q1 * k4.z; sc[1][3] += q1 * k4.w;
      sc[0][0] += q0 * p1; sc[0][1] += q0 * p2;
      sc[0][2] += q0 * p3; sc[0][3] += q0 * p4;
      sc[1][0] += q1 * p0; sc[1][1] += q1 * p1;
      sc[1][2] += q1 * p2; sc[1][3] += q1 * p3;
    }
    float sfull[2][4];
#pragma unroll
    for (int it = 0; it < 2; ++it)
#pragma unroll
      for (int js = 0; js < 4; ++js) {
        const int li = lb + js + (it == 0 ? 1 : 0);
        sfull[it][js] = 0.125f * (sc[it][js] + uk_t[sA + js] + vp_w[li]);
      }

    // ---- online softmax (8-lane row groups, wave-synchronous) ----
#pragma unroll
    for (int it = 0; it < 2; ++it) {
      const int t = tA + it;
      float tmax = fmaxf(fmaxf(sfull[it][0], sfull[it][1]),
                         fmaxf(sfull[it][2], sfull[it][3]));
      tmax = fmaxf(tmax, __shfl_xor(tmax, 1));
      tmax = fmaxf(tmax, __shfl_xor(tmax, 2));
      tmax = fmaxf(tmax, __shfl_xor(tmax, 4));
      const float m_old = m_row[t];          // read before lane-0 write (lockstep)
      const float m_new = fmaxf(m_old, tmax);
      const float alpha = __expf(m_old - m_new);
      float pr[4], rsum = 0.f;
#pragma unroll
      for (int js = 0; js < 4; ++js) {
        pr[js] = __expf(sfull[it][js] - m_new);
        rsum += pr[js];
      }
      rsum += __shfl_xor(rsum, 1);
      rsum += __shfl_xor(rsum, 2);
      rsum += __shfl_xor(rsum, 4);
      if (txS == 0) {
        m_row[t] = m_new;
        alpha_row[t] = alpha;
        l_row[t] = l_row[t] * alpha + rsum;
      }
#pragma unroll
      for (int js = 0; js < 4; ++js) Pm[t][sA + js] = pr[js];
    }
    __syncthreads();

    // ---- AV accumulate: rows (ty*4..+3), cols (tx*4..+3) ----
#pragma unroll
    for (int it = 0; it < 4; ++it) {
      const float a_r = alpha_row[(ty << 2) + it];
      acc[it][0] *= a_r; acc[it][1] *= a_r;
      acc[it][2] *= a_r; acc[it][3] *= a_r;
    }
#pragma unroll 4
    for (int s = 0; s < ST; ++s) {
      const float4 vv = *(const float4*)&vs[s][tx << 2];
      const float p0 = Pm[(ty << 2) + 0][s], p1 = Pm[(ty << 2) + 1][s];
      const float p2 = Pm[(ty << 2) + 2][s], p3 = Pm[(ty << 2) + 3][s];
      acc[0][0] += p0 * vv.x; acc[0][1] += p0 * vv.y;
      acc[0][2] += p0 * vv.z; acc[0][3] += p0 * vv.w;
      acc[1][0] += p1 * vv.x; acc[1][1] += p1 * vv.y;
      acc[1][2] += p1 * vv.z; acc[1][3] += p1 * vv.w;
      acc[2][0] += p2 * vv.x; acc[2][1] += p2 * vv.y;
      acc[2][2] += p2 * vv.z; acc[2][3] += p2 * vv.w;
      acc[3][0] += p3 * vv.x; acc[3][1] += p3 * vv.y;
      acc[3][2] += p3 * vv.z; acc[3][3] += p3 * vv.w;
    }
    __syncthreads();
  }

  // ---- finalize: x[b, t, h, :] stored at [T,B,C] ----
#pragma unroll
  for (int it = 0; it < 4; ++it) {
    const int t = (ty << 2) + it;
    const float inv_l = 1.f / l_row[t];
    float4 o;
    o.x = acc[it][0] * inv_l; o.y = acc[it][1] * inv_l;
    o.z = acc[it][2] * inv_l; o.w = acc[it][3] * inv_l;
    *(float4*)&x[((size_t)(t0 + t) * NB + b) * CC + h * DD + (tx << 2)] = o;
  }
}

// ---------------------------------------------------------------------------
extern "C" void kernel_launch(void* const* d_in, const int* in_sizes, int n_in,
                              void* d_out, int out_size, void* d_ws, size_t ws_size,
                              hipStream_t stream) {
  const float* query   = (const float*)d_in[0];
  const float* key_    = (const float*)d_in[1];
  const float* value   = (const float*)d_in[2];
  const float* pos_emb = (const float*)d_in[3];
  const float* Wq  = (const float*)d_in[4];
  const float* bq  = (const float*)d_in[5];
  const float* Wk  = (const float*)d_in[6];
  const float* bk  = (const float*)d_in[7];
  const float* Wv  = (const float*)d_in[8];
  const float* bv  = (const float*)d_in[9];
  const float* Wp  = (const float*)d_in[10];
  const float* Wo  = (const float*)d_in[11];
  const float* bo  = (const float*)d_in[12];
  const float* pbu = (const float*)d_in[13];
  const float* pbv = (const float*)d_in[14];
  float* out = (float*)d_out;

  // workspace layout (floats)
  float* ws = (float*)d_ws;
  float* q  = ws;                    // 4096*1024
  float* k  = ws + 4194304;          // 4096*1024
  float* v  = ws + 8388608;          // 4096*1024
  float* pp = ws + 12582912;         // 2047*1024
  float* x  = ws + 14679040;         // 4096*1024
  float* uk = ws + 18873344;         // 65536
  float* vp = ws + 18938880;         // 2047*16
  // total = 18971632 floats = ~75.9 MB

  const dim3 blk(256);
  // projections: rows are (t*B+b), i.e. [T,B,C] flat = [4096,1024]
  gemm_nt<<<dim3(16, 64), blk, 0, stream>>>(query,   Wq, bq,      q,  4096, 1024, 1024);
  gemm_nt<<<dim3(16, 64), blk, 0, stream>>>(key_,    Wk, bk,      k,  4096, 1024, 1024);
  gemm_nt<<<dim3(16, 64), blk, 0, stream>>>(value,   Wv, bv,      v,  4096, 1024, 1024);
  gemm_nt<<<dim3(16, 32), blk, 0, stream>>>(pos_emb, Wp, nullptr, pp, 2047, 1024, 1024);
  precompute_kernel<<<dim3(384), blk, 0, stream>>>(k, pp, pbu, pbv, uk, vp);
  attn_kernel<<<dim3(T_SEQ / TQ, NH, NB), blk, 0, stream>>>(q, k, v, pp, uk, vp, x);
  gemm_nt<<<dim3(16, 64), blk, 0, stream>>>(x, Wo, bo, out, 4096, 1024, 1024);
}

// Round 3
// 588.560 us; speedup vs baseline: 2.4420x; 2.4420x over previous
//
#include <hip/hip_runtime.h>
#include <hip/hip_bf16.h>
#include <math.h>

// Problem: T=1024, B=4, H=16, D=64, C=1024.
#define T_SEQ 1024
#define NB 4
#define NH 16
#define DD 64
#define CC 1024

typedef __attribute__((ext_vector_type(8))) short short8;   // 8 x bf16 (4 VGPR)
typedef __attribute__((ext_vector_type(4))) float floatx4;  // MFMA C/D
typedef __attribute__((ext_vector_type(4))) unsigned short ushort4v;

#define MFMA(a, b, c) __builtin_amdgcn_mfma_f32_16x16x32_bf16((a), (b), (c), 0, 0, 0)

__device__ inline float bf2f(unsigned short u) {
  union { unsigned int i; float f; } c; c.i = ((unsigned int)u) << 16; return c.f;
}
__device__ inline unsigned short f2bf(float x) {
  union { float f; unsigned int i; } c; c.f = x;
  unsigned int u = c.i;
  u += 0x7fff + ((u >> 16) & 1);   // RNE (inputs are finite)
  return (unsigned short)(u >> 16);
}

// ---------------------------------------------------------------------------
// bf16 MFMA GEMM: C[m,n] = sum_k A[m,k]*W[n,k] (+bias[n])
// A: fp32 or bf16 row-major [M,K]; W fp32 [N,K] (converted in-flight).
// 128x128 tile, 256 threads, 4 waves in 2x2, each wave 64x64 (4x4 C-frags).
// ---------------------------------------------------------------------------
template <int A_BF16, int OUT_BF16>
__global__ __launch_bounds__(256) void gemm_nt(
    const void* __restrict__ Av, const float* __restrict__ W,
    const float* __restrict__ bias, void* __restrict__ Cv,
    int M_real, int N, int K)
{
  __shared__ __align__(16) unsigned short As[128 * 40];
  __shared__ __align__(16) unsigned short Bs[128 * 40];

  const int tid = threadIdx.x;
  const int lane = tid & 63;
  const int w = tid >> 6;
  const int l15 = lane & 15, quad = lane >> 4;
  const int rw = (w >> 1) * 64, cw = (w & 1) * 64;
  const int bm = blockIdx.y * 128, bn = blockIdx.x * 128;

  floatx4 acc[4][4];
#pragma unroll
  for (int i = 0; i < 4; ++i)
#pragma unroll
    for (int j = 0; j < 4; ++j) acc[i][j] = (floatx4){0.f, 0.f, 0.f, 0.f};

  for (int k0 = 0; k0 < K; k0 += 32) {
#pragma unroll
    for (int cc = 0; cc < 2; ++cc) {
      const int idx = tid + cc * 256;
      const int row = idx >> 2, kc = idx & 3;
      {
        short8 val;
        if (A_BF16) {
          if (bm + row < M_real)
            val = *(const short8*)((const unsigned short*)Av + (size_t)(bm + row) * K + k0 + kc * 8);
          else
            val = (short8){0, 0, 0, 0, 0, 0, 0, 0};
        } else {
          if (bm + row < M_real) {
            const float* ap = (const float*)Av + (size_t)(bm + row) * K + k0 + kc * 8;
            const float4 a0 = *(const float4*)(ap);
            const float4 a1 = *(const float4*)(ap + 4);
            val = (short8){(short)f2bf(a0.x), (short)f2bf(a0.y), (short)f2bf(a0.z), (short)f2bf(a0.w),
                           (short)f2bf(a1.x), (short)f2bf(a1.y), (short)f2bf(a1.z), (short)f2bf(a1.w)};
          } else {
            val = (short8){0, 0, 0, 0, 0, 0, 0, 0};
          }
        }
        *(short8*)&As[row * 40 + kc * 8] = val;
      }
      {
        const float* wp = W + (size_t)(bn + row) * K + k0 + kc * 8;
        const float4 b0 = *(const float4*)(wp);
        const float4 b1 = *(const float4*)(wp + 4);
        short8 val = (short8){(short)f2bf(b0.x), (short)f2bf(b0.y), (short)f2bf(b0.z), (short)f2bf(b0.w),
                              (short)f2bf(b1.x), (short)f2bf(b1.y), (short)f2bf(b1.z), (short)f2bf(b1.w)};
        *(short8*)&Bs[row * 40 + kc * 8] = val;
      }
    }
    __syncthreads();

    short8 af[4], bfr[4];
#pragma unroll
    for (int i = 0; i < 4; ++i)
      af[i] = *(short8*)&As[(rw + i * 16 + l15) * 40 + quad * 8];
#pragma unroll
    for (int j = 0; j < 4; ++j)
      bfr[j] = *(short8*)&Bs[(cw + j * 16 + l15) * 40 + quad * 8];
#pragma unroll
    for (int i = 0; i < 4; ++i)
#pragma unroll
      for (int j = 0; j < 4; ++j)
        acc[i][j] = MFMA(af[i], bfr[j], acc[i][j]);
    __syncthreads();
  }

#pragma unroll
  for (int j = 0; j < 4; ++j) {
    const int col = bn + cw + j * 16 + l15;
    const float bj = bias ? bias[col] : 0.f;
#pragma unroll
    for (int i = 0; i < 4; ++i) {
      const int row0 = bm + rw + i * 16 + quad * 4;
#pragma unroll
      for (int reg = 0; reg < 4; ++reg) {
        const float v = acc[i][j][reg] + bj;
        if (OUT_BF16)
          ((unsigned short*)Cv)[(size_t)(row0 + reg) * N + col] = f2bf(v);
        else
          ((float*)Cv)[(size_t)(row0 + reg) * N + col] = v;
      }
    }
  }
}

// ---------------------------------------------------------------------------
// Transpose V per (b,h): vb rows (t*4+b), cols h*64+d  ->  vT[b][h][d][t]
// ---------------------------------------------------------------------------
__global__ __launch_bounds__(256) void transpose_v(
    const unsigned short* __restrict__ vb, unsigned short* __restrict__ vT)
{
  __shared__ __align__(16) unsigned short Lt[64 * 136];
  const int t0 = blockIdx.x * 128;
  const int h = blockIdx.y, b = blockIdx.z;
  const int tid = threadIdx.x;

#pragma unroll
  for (int cc = 0; cc < 4; ++cc) {
    const int idx = tid + cc * 256;
    const int r = idx >> 3, pc = idx & 7;
    short8 val = *(const short8*)(vb + ((size_t)((t0 + r) * 4 + b)) * 1024 + h * 64 + pc * 8);
#pragma unroll
    for (int e = 0; e < 8; ++e)
      Lt[(pc * 8 + e) * 136 + r] = (unsigned short)val[e];
  }
  __syncthreads();
#pragma unroll
  for (int cc = 0; cc < 4; ++cc) {
    const int idx = tid + cc * 256;
    const int d = idx >> 4, tc = idx & 15;
    short8 v2 = *(short8*)&Lt[d * 136 + tc * 8];
    *(short8*)(vT + ((size_t)((b * 16 + h) * 64 + d)) * 1024 + t0 + tc * 8) = v2;
  }
}

// ---------------------------------------------------------------------------
// Precompute rank-1 bias dots: uk[(b*16+h)*1024+s] = pbu[h]·k[b,s,h]
//                              vp[idx*16+h]        = pbv[h]·p[idx,h]
// ---------------------------------------------------------------------------
__global__ __launch_bounds__(256) void precompute_kernel(
    const unsigned short* __restrict__ kb, const unsigned short* __restrict__ pb,
    const float* __restrict__ pbu, const float* __restrict__ pbv,
    float* __restrict__ uk, float* __restrict__ vp)
{
  const int i = blockIdx.x * 256 + threadIdx.x;
  if (i < 65536) {
    const int b = i >> 14, h = (i >> 10) & 15, s = i & 1023;
    const unsigned short* kr = kb + ((size_t)(s * 4 + b)) * 1024 + h * 64;
    const float* ur = pbu + h * 64;
    float sum = 0.f;
#pragma unroll
    for (int c = 0; c < 8; ++c) {
      short8 kv = *(const short8*)(kr + c * 8);
#pragma unroll
      for (int e = 0; e < 8; ++e) sum += bf2f((unsigned short)kv[e]) * ur[c * 8 + e];
    }
    uk[i] = sum;
  } else if (i < 98304) {
    const int j = i - 65536;
    const int idx = j >> 4, h = j & 15;
    const unsigned short* pr = pb + (size_t)idx * 1024 + h * 64;
    const float* vr = pbv + h * 64;
    float sum = 0.f;
#pragma unroll
    for (int c = 0; c < 8; ++c) {
      short8 pv = *(const short8*)(pr + c * 8);
#pragma unroll
      for (int e = 0; e < 8; ++e) sum += bf2f((unsigned short)pv[e]) * vr[c * 8 + e];
    }
    vp[(idx << 4) + h] = sum;
  }
}

// ---------------------------------------------------------------------------
// Fused rel-pos MFMA attention (flash-style, transposed scores).
// Per block: (b,h,64-row q-tile). 4 waves: sh=w>>1 (s/jj/d half), th=w&1 (t half).
// St[s,t] = K·Q^T (MFMA, frags direct from global).
// BDskewT[jj,t] = Pwin·Q^T (MFMA), jj = s-t+63; round-trip via LDS in FP32.
// P^T packed to LDS (b64), PV via MFMA with pre-transposed V (global).
// ---------------------------------------------------------------------------
__global__ __launch_bounds__(256) void attn_kernel(
    const unsigned short* __restrict__ qb, const unsigned short* __restrict__ kb,
    const unsigned short* __restrict__ pb, const unsigned short* __restrict__ vT,
    const float* __restrict__ uk, const float* __restrict__ vp,
    unsigned short* __restrict__ xb)
{
  __shared__ __align__(16) unsigned short Pb[64 * 136];  // P[t][s] bf16
  __shared__ __align__(16) float BDf[64 * 196];          // BD[t][jj] fp32
  __shared__ float uk_s[128], vp_w[192];
  __shared__ float pmax[2][64], psum[2][64];
  __shared__ float m_row[64], l_row[64], alpha_row[64];

  const int tid = threadIdx.x;
  const int lane = tid & 63;
  const int w = tid >> 6;
  const int l15 = lane & 15, quad = lane >> 4;
  const int th = w & 1, sh = w >> 1;

  // XCD swizzle: cluster all 16 q-tiles of a (b,h) on one XCD for L2 reuse.
  const int flat = blockIdx.x + (blockIdx.y << 4) + (blockIdx.z << 8);
  const int x8 = flat & 7, s8 = flat >> 3;
  const int hb = x8 * 8 + (s8 >> 4);
  const int t0 = (s8 & 15) * 64;
  const int b = hb >> 4, h = hb & 15;

  // Q as MFMA B-operand: B[k=d][n=t], lane n=l15, k=quad*8+j. qf[ttile][kstep]
  short8 qf[2][2];
#pragma unroll
  for (int tt = 0; tt < 2; ++tt)
#pragma unroll
    for (int kk = 0; kk < 2; ++kk) {
      const int t = t0 + th * 32 + tt * 16 + l15;
      qf[tt][kk] = *(const short8*)(qb + ((size_t)(t * 4 + b)) * 1024 + h * 64 + kk * 32 + quad * 8);
    }

  floatx4 of[2][2];  // O[t-tile][d-tile], rows t=quad*4+reg, cols d=l15
#pragma unroll
  for (int i = 0; i < 2; ++i)
#pragma unroll
    for (int j = 0; j < 2; ++j) of[i][j] = (floatx4){0.f, 0.f, 0.f, 0.f};

  if (tid < 64) { m_row[tid] = -3.0e38f; l_row[tid] = 0.f; }
  __syncthreads();

  for (int s0 = 0; s0 < 1024; s0 += 128) {
    const int w0 = s0 - t0 + 960;  // global p row of jj=0

    // ---- Phase 1: stage uk/vp, BD MFMA + BDf write, AC MFMA ----
    if (tid < 128) uk_s[tid] = uk[((b * 16 + h) << 10) + s0 + tid];
    if (tid < 192) vp_w[tid] = vp[(((size_t)(w0 + tid)) << 4) + h];

    {
      floatx4 bd[6][2];
#pragma unroll
      for (int jt = 0; jt < 6; ++jt) {
        const int jj = sh * 96 + jt * 16 + l15;
        const unsigned short* pr = pb + ((size_t)(w0 + jj)) * 1024 + h * 64;
        short8 pf0 = *(const short8*)(pr + quad * 8);
        short8 pf1 = *(const short8*)(pr + 32 + quad * 8);
#pragma unroll
        for (int tt = 0; tt < 2; ++tt) {
          floatx4 z = (floatx4){0.f, 0.f, 0.f, 0.f};
          z = MFMA(pf0, qf[tt][0], z);
          z = MFMA(pf1, qf[tt][1], z);
          bd[jt][tt] = z;
        }
      }
#pragma unroll
      for (int jt = 0; jt < 6; ++jt)
#pragma unroll
        for (int tt = 0; tt < 2; ++tt) {
          const int tloc = th * 32 + tt * 16 + l15;
          const int jjb = sh * 96 + jt * 16 + quad * 4;
          *(float4*)&BDf[tloc * 196 + jjb] =
              make_float4(bd[jt][tt][0], bd[jt][tt][1], bd[jt][tt][2], bd[jt][tt][3]);
        }
    }

    floatx4 st[4][2];  // St[s-tile][t-tile]: rows s=quad*4+reg, cols t=l15
#pragma unroll
    for (int stile = 0; stile < 4; ++stile) {
      const int srow = s0 + sh * 64 + stile * 16 + l15;
      const unsigned short* kr = kb + ((size_t)(srow * 4 + b)) * 1024 + h * 64;
      short8 kf0 = *(const short8*)(kr + quad * 8);
      short8 kf1 = *(const short8*)(kr + 32 + quad * 8);
#pragma unroll
      for (int tt = 0; tt < 2; ++tt) {
        floatx4 z = (floatx4){0.f, 0.f, 0.f, 0.f};
        z = MFMA(kf0, qf[tt][0], z);
        z = MFMA(kf1, qf[tt][1], z);
        st[stile][tt] = z;
      }
    }
    __syncthreads();  // B_a

    // ---- Phase 2: assemble scores + per-t local max ----
    float lmax[2] = {-3.0e38f, -3.0e38f};
#pragma unroll
    for (int stile = 0; stile < 4; ++stile)
#pragma unroll
      for (int tt = 0; tt < 2; ++tt) {
        const int tloc = th * 32 + tt * 16 + l15;
#pragma unroll
        for (int reg = 0; reg < 4; ++reg) {
          const int sloc = sh * 64 + stile * 16 + quad * 4 + reg;
          const int jj = sloc - tloc + 63;
          float v = 0.125f * (st[stile][tt][reg] + BDf[tloc * 196 + jj] +
                              uk_s[sloc] + vp_w[jj]);
          st[stile][tt][reg] = v;
          lmax[tt] = fmaxf(lmax[tt], v);
        }
      }
#pragma unroll
    for (int tt = 0; tt < 2; ++tt) {
      lmax[tt] = fmaxf(lmax[tt], __shfl_xor(lmax[tt], 16));
      lmax[tt] = fmaxf(lmax[tt], __shfl_xor(lmax[tt], 32));
    }
    if (quad == 0) {
      pmax[sh][th * 32 + l15] = lmax[0];
      pmax[sh][th * 32 + 16 + l15] = lmax[1];
    }
    __syncthreads();  // B_b

    // ---- Phase 3: per-row m/alpha update ----
    if (tid < 64) {
      const float mo = m_row[tid];
      const float mn = fmaxf(mo, fmaxf(pmax[0][tid], pmax[1][tid]));
      alpha_row[tid] = __expf(mo - mn);
      m_row[tid] = mn;
    }
    __syncthreads();  // B_c

    // ---- Phase 4: P=exp, Pb write, psum, O rescale ----
    float lsum[2] = {0.f, 0.f};
    float mt[2];
#pragma unroll
    for (int tt = 0; tt < 2; ++tt) mt[tt] = m_row[th * 32 + tt * 16 + l15];
#pragma unroll
    for (int stile = 0; stile < 4; ++stile)
#pragma unroll
      for (int tt = 0; tt < 2; ++tt) {
        float p0 = __expf(st[stile][tt][0] - mt[tt]);
        float p1 = __expf(st[stile][tt][1] - mt[tt]);
        float p2 = __expf(st[stile][tt][2] - mt[tt]);
        float p3 = __expf(st[stile][tt][3] - mt[tt]);
        lsum[tt] += p0 + p1 + p2 + p3;
        const int tloc = th * 32 + tt * 16 + l15;
        const int sb = sh * 64 + stile * 16 + quad * 4;
        ushort4v pk = (ushort4v){f2bf(p0), f2bf(p1), f2bf(p2), f2bf(p3)};
        *(ushort4v*)&Pb[tloc * 136 + sb] = pk;
      }
#pragma unroll
    for (int tt = 0; tt < 2; ++tt) {
      lsum[tt] += __shfl_xor(lsum[tt], 16);
      lsum[tt] += __shfl_xor(lsum[tt], 32);
    }
    if (quad == 0) {
      psum[sh][th * 32 + l15] = lsum[0];
      psum[sh][th * 32 + 16 + l15] = lsum[1];
    }
#pragma unroll
    for (int tt = 0; tt < 2; ++tt)
#pragma unroll
      for (int reg = 0; reg < 4; ++reg) {
        const float ar = alpha_row[th * 32 + tt * 16 + quad * 4 + reg];
        of[tt][0][reg] *= ar;
        of[tt][1][reg] *= ar;
      }
    __syncthreads();  // B_d

    // ---- Phase 5: l update + PV MFMA ----
    if (tid < 64)
      l_row[tid] = l_row[tid] * alpha_row[tid] + psum[0][tid] + psum[1][tid];
#pragma unroll
    for (int kk2 = 0; kk2 < 4; ++kk2) {
      short8 pa[2], vf[2];
#pragma unroll
      for (int tt = 0; tt < 2; ++tt)
        pa[tt] = *(short8*)&Pb[(th * 32 + tt * 16 + l15) * 136 + kk2 * 32 + quad * 8];
#pragma unroll
      for (int dt = 0; dt < 2; ++dt)
        vf[dt] = *(const short8*)(vT + ((size_t)((b * 16 + h) * 64 + sh * 32 + dt * 16 + l15)) * 1024 +
                                  s0 + kk2 * 32 + quad * 8);
#pragma unroll
      for (int tt = 0; tt < 2; ++tt)
#pragma unroll
        for (int dt = 0; dt < 2; ++dt)
          of[tt][dt] = MFMA(pa[tt], vf[dt], of[tt][dt]);
    }
  }
  __syncthreads();  // l_row final visibility

#pragma unroll
  for (int tt = 0; tt < 2; ++tt)
#pragma unroll
    for (int reg = 0; reg < 4; ++reg) {
      const int t = th * 32 + tt * 16 + quad * 4 + reg;
      const float il = 1.f / l_row[t];
#pragma unroll
      for (int dt = 0; dt < 2; ++dt) {
        const int d = sh * 32 + dt * 16 + l15;
        xb[((size_t)((t0 + t) * 4 + b)) * 1024 + h * 64 + d] = f2bf(of[tt][dt][reg] * il);
      }
    }
}

// ---------------------------------------------------------------------------
extern "C" void kernel_launch(void* const* d_in, const int* in_sizes, int n_in,
                              void* d_out, int out_size, void* d_ws, size_t ws_size,
                              hipStream_t stream) {
  const float* query   = (const float*)d_in[0];
  const float* key_    = (const float*)d_in[1];
  const float* value   = (const float*)d_in[2];
  const float* pos_emb = (const float*)d_in[3];
  const float* Wq  = (const float*)d_in[4];
  const float* bq  = (const float*)d_in[5];
  const float* Wk  = (const float*)d_in[6];
  const float* bk  = (const float*)d_in[7];
  const float* Wv  = (const float*)d_in[8];
  const float* bv  = (const float*)d_in[9];
  const float* Wp  = (const float*)d_in[10];
  const float* Wo  = (const float*)d_in[11];
  const float* bo  = (const float*)d_in[12];
  const float* pbu = (const float*)d_in[13];
  const float* pbv = (const float*)d_in[14];
  float* out = (float*)d_out;

  // workspace (ushort elements), ~38.1 MB total
  unsigned short* U = (unsigned short*)d_ws;
  unsigned short* qb  = U;                  // 4096x1024
  unsigned short* kb  = U + 4194304;        // 4096x1024
  unsigned short* pb  = U + 8388608;        // 2048x1024 (row 2047 = 0 pad)
  unsigned short* vTb = U + 10485760;       // [b][h][64][1024]
  unsigned short* xb  = U + 14680064;       // 4096x1024 (first holds v-proj)
  float* fbase = (float*)(U + 18874368);
  float* uk = fbase;                        // 4*16*1024
  float* vp = fbase + 65536;                // 2048*16

  const dim3 blk(256);
  // projections (A fp32 -> bf16 out)
  gemm_nt<0, 1><<<dim3(8, 32), blk, 0, stream>>>(query,   Wq, bq,      qb, 4096, 1024, 1024);
  gemm_nt<0, 1><<<dim3(8, 32), blk, 0, stream>>>(key_,    Wk, bk,      kb, 4096, 1024, 1024);
  gemm_nt<0, 1><<<dim3(8, 32), blk, 0, stream>>>(value,   Wv, bv,      xb, 4096, 1024, 1024);
  gemm_nt<0, 1><<<dim3(8, 16), blk, 0, stream>>>(pos_emb, Wp, nullptr, pb, 2047, 1024, 1024);
  transpose_v<<<dim3(8, 16, 4), blk, 0, stream>>>(xb, vTb);
  precompute_kernel<<<dim3(384), blk, 0, stream>>>(kb, pb, pbu, pbv, uk, vp);
  attn_kernel<<<dim3(16, 16, 4), blk, 0, stream>>>(qb, kb, pb, vTb, uk, vp, xb);
  // output projection (A bf16 -> fp32 out + bias)
  gemm_nt<1, 0><<<dim3(8, 32), blk, 0, stream>>>(xb, Wo, bo, out, 4096, 1024, 1024);
}

// Round 4
// 352.805 us; speedup vs baseline: 4.0739x; 1.6682x over previous
//
#include <hip/hip_runtime.h>
#include <hip/hip_bf16.h>
#include <math.h>

// Problem: T=1024, B=4, H=16, D=64, C=1024.
#define T_SEQ 1024
#define NB 4
#define NH 16
#define DD 64
#define CC 1024

typedef __attribute__((ext_vector_type(8))) short short8;   // 8 x bf16 (4 VGPR)
typedef __attribute__((ext_vector_type(4))) float floatx4;  // MFMA C/D
typedef __attribute__((ext_vector_type(4))) unsigned short ushort4v;

#define MFMA(a, b, c) __builtin_amdgcn_mfma_f32_16x16x32_bf16((a), (b), (c), 0, 0, 0)

__device__ inline float bf2f(unsigned short u) {
  union { unsigned int i; float f; } c; c.i = ((unsigned int)u) << 16; return c.f;
}
__device__ inline unsigned short f2bf(float x) {
  union { float f; unsigned int i; } c; c.f = x;
  unsigned int u = c.i;
  u += 0x7fff + ((u >> 16) & 1);   // RNE (inputs are finite)
  return (unsigned short)(u >> 16);
}

// async global->LDS, 16B per lane; LDS dest = wave-uniform base + lane*16
__device__ __forceinline__ void gload_lds16(const void* g, void* l) {
  __builtin_amdgcn_global_load_lds(
      (const __attribute__((address_space(1))) unsigned int*)g,
      (__attribute__((address_space(3))) unsigned int*)l, 16, 0, 0);
}

// ---------------------------------------------------------------------------
// Convert pass: fp32 -> bf16 for q/k/v inputs, pos_emb (padded to 2048 rows),
// and the 5 weight matrices. One vec8 per thread.
// ---------------------------------------------------------------------------
__global__ __launch_bounds__(256) void convert_kernel(
    const float* __restrict__ q, const float* __restrict__ k,
    const float* __restrict__ v, const float* __restrict__ pe_in,
    const float* __restrict__ wq, const float* __restrict__ wk,
    const float* __restrict__ wv, const float* __restrict__ wp,
    const float* __restrict__ wo,
    unsigned short* __restrict__ qo, unsigned short* __restrict__ ko,
    unsigned short* __restrict__ vo, unsigned short* __restrict__ po,
    unsigned short* __restrict__ wqo, unsigned short* __restrict__ wko,
    unsigned short* __restrict__ wvo, unsigned short* __restrict__ wpo,
    unsigned short* __restrict__ woo)
{
  const int i = blockIdx.x * 256 + threadIdx.x;  // vec8 index
  const float* src; unsigned short* dst; int off;
  if      (i < 524288)  { src = q;     dst = qo;  off = i; }
  else if (i < 1048576) { src = k;     dst = ko;  off = i - 524288; }
  else if (i < 1572864) { src = v;     dst = vo;  off = i - 1048576; }
  else if (i < 1834880) { src = pe_in; dst = po;  off = i - 1572864; }
  else if (i < 1965952) { src = wq;    dst = wqo; off = i - 1834880; }
  else if (i < 2097024) { src = wk;    dst = wko; off = i - 1965952; }
  else if (i < 2228096) { src = wv;    dst = wvo; off = i - 2097024; }
  else if (i < 2359168) { src = wp;    dst = wpo; off = i - 2228096; }
  else if (i < 2490240) { src = wo;    dst = woo; off = i - 2359168; }
  else {  // zero-fill pos_emb pad row 2047 (128 vec8 = 1024 elems)
    const int j = i - 2490240;
    *(short8*)&po[2047 * 1024 + j * 8] = (short8){0, 0, 0, 0, 0, 0, 0, 0};
    return;
  }
  const float4 a0 = *(const float4*)(src + (size_t)off * 8);
  const float4 a1 = *(const float4*)(src + (size_t)off * 8 + 4);
  short8 val = (short8){(short)f2bf(a0.x), (short)f2bf(a0.y), (short)f2bf(a0.z), (short)f2bf(a0.w),
                        (short)f2bf(a1.x), (short)f2bf(a1.y), (short)f2bf(a1.z), (short)f2bf(a1.w)};
  *(short8*)&dst[(size_t)off * 8] = val;
}

// ---------------------------------------------------------------------------
// m97-pattern bf16 MFMA GEMM core: C[m,n] = sum_k A[m,k]*W[n,k] (+bias[n])
// A,W bf16 row-major [*,K]; 128x128 tile, BK=32, global_load_lds staging.
// 4 waves 2x2, each 64x64 (4x4 C-frags). M,N multiples of 128.
// ---------------------------------------------------------------------------
template <int OUT_BF16>
__device__ __forceinline__ void gemm_core(
    const unsigned short* __restrict__ A, const unsigned short* __restrict__ Wt,
    const float* __restrict__ bias, void* __restrict__ Cv,
    unsigned short* As, unsigned short* Bs, int N, int K, int bm, int bn)
{
  const int tid = threadIdx.x;
  const int lane = tid & 63;
  const int w = tid >> 6;
  const int l15 = lane & 15, quad = lane >> 4;
  const int rw = (w >> 1) * 64, cw = (w & 1) * 64;

  floatx4 acc[4][4];
#pragma unroll
  for (int i = 0; i < 4; ++i)
#pragma unroll
    for (int j = 0; j < 4; ++j) acc[i][j] = (floatx4){0.f, 0.f, 0.f, 0.f};

  // staging: wave w covers rows [w*32, w*32+32); lane L -> row +(L>>2), col8 (L&3)
  const int lrow = lane >> 2, lcol = (lane & 3) * 8;
  const unsigned short* Ag = A + (size_t)(bm + w * 32 + lrow) * K + lcol;
  const unsigned short* Wg = Wt + (size_t)(bn + w * 32 + lrow) * K + lcol;
  unsigned short* AsW = As + w * 1024;  // 32 rows * 32 cols
  unsigned short* BsW = Bs + w * 1024;

  for (int k0 = 0; k0 < K; k0 += 32) {
    gload_lds16(Ag + k0, AsW);
    gload_lds16(Ag + 16 * K + k0, AsW + 512);
    gload_lds16(Wg + k0, BsW);
    gload_lds16(Wg + 16 * K + k0, BsW + 512);
    __syncthreads();  // waits vmcnt(0): DMA complete

    short8 af[4], bfr[4];
#pragma unroll
    for (int i = 0; i < 4; ++i)
      af[i] = *(short8*)&As[(rw + i * 16 + l15) * 32 + quad * 8];
#pragma unroll
    for (int j = 0; j < 4; ++j)
      bfr[j] = *(short8*)&Bs[(cw + j * 16 + l15) * 32 + quad * 8];
#pragma unroll
    for (int i = 0; i < 4; ++i)
#pragma unroll
      for (int j = 0; j < 4; ++j)
        acc[i][j] = MFMA(af[i], bfr[j], acc[i][j]);
    __syncthreads();  // all waves done reading before next DMA
  }

#pragma unroll
  for (int j = 0; j < 4; ++j) {
    const int col = bn + cw + j * 16 + l15;
    const float bj = bias ? bias[col] : 0.f;
#pragma unroll
    for (int i = 0; i < 4; ++i) {
      const int row0 = bm + rw + i * 16 + quad * 4;
#pragma unroll
      for (int reg = 0; reg < 4; ++reg) {
        const float v = acc[i][j][reg] + bj;
        if (OUT_BF16)
          ((unsigned short*)Cv)[(size_t)(row0 + reg) * N + col] = f2bf(v);
        else
          ((float*)Cv)[(size_t)(row0 + reg) * N + col] = v;
      }
    }
  }
}

struct GemmJob { const unsigned short* A; const unsigned short* Wt;
                 const float* bias; unsigned short* C; int mtiles; };
struct GemmJobs { GemmJob j[3]; };

// Fused Q,K,P projection GEMMs (z picks job; P has 16 m-tiles).
__global__ __launch_bounds__(256) void gemm_qkp(GemmJobs jobs) {
  __shared__ __align__(16) unsigned short As[128 * 32];
  __shared__ __align__(16) unsigned short Bs[128 * 32];
  GemmJob jb = jobs.j[blockIdx.z];
  if ((int)blockIdx.y >= jb.mtiles) return;
  gemm_core<1>(jb.A, jb.Wt, jb.bias, jb.C, As, Bs, 1024, 1024,
               blockIdx.y * 128, blockIdx.x * 128);
}

template <int OUT_BF16>
__global__ __launch_bounds__(256) void gemm_one(
    const unsigned short* __restrict__ A, const unsigned short* __restrict__ Wt,
    const float* __restrict__ bias, void* __restrict__ Cv) {
  __shared__ __align__(16) unsigned short As[128 * 32];
  __shared__ __align__(16) unsigned short Bs[128 * 32];
  gemm_core<OUT_BF16>(A, Wt, bias, Cv, As, Bs, 1024, 1024,
                      blockIdx.y * 128, blockIdx.x * 128);
}

// ---------------------------------------------------------------------------
// Transpose V per (b,h): vb rows (t*4+b), cols h*64+d  ->  vT[b][h][d][t]
// ---------------------------------------------------------------------------
__global__ __launch_bounds__(256) void transpose_v(
    const unsigned short* __restrict__ vb, unsigned short* __restrict__ vT)
{
  __shared__ __align__(16) unsigned short Lt[64 * 136];
  const int t0 = blockIdx.x * 128;
  const int h = blockIdx.y, b = blockIdx.z;
  const int tid = threadIdx.x;

#pragma unroll
  for (int cc = 0; cc < 4; ++cc) {
    const int idx = tid + cc * 256;
    const int r = idx >> 3, pc = idx & 7;
    short8 val = *(const short8*)(vb + ((size_t)((t0 + r) * 4 + b)) * 1024 + h * 64 + pc * 8);
#pragma unroll
    for (int e = 0; e < 8; ++e)
      Lt[(pc * 8 + e) * 136 + r] = (unsigned short)val[e];
  }
  __syncthreads();
#pragma unroll
  for (int cc = 0; cc < 4; ++cc) {
    const int idx = tid + cc * 256;
    const int d = idx >> 4, tc = idx & 15;
    short8 v2 = *(short8*)&Lt[d * 136 + tc * 8];
    *(short8*)(vT + ((size_t)((b * 16 + h) * 64 + d)) * 1024 + t0 + tc * 8) = v2;
  }
}

// ---------------------------------------------------------------------------
// Precompute rank-1 bias dots: uk[(b*16+h)*1024+s] = pbu[h]·k[b,s,h]
//                              vp[idx*16+h]        = pbv[h]·p[idx,h]
// ---------------------------------------------------------------------------
__global__ __launch_bounds__(256) void precompute_kernel(
    const unsigned short* __restrict__ kb, const unsigned short* __restrict__ pb,
    const float* __restrict__ pbu, const float* __restrict__ pbv,
    float* __restrict__ uk, float* __restrict__ vp)
{
  const int i = blockIdx.x * 256 + threadIdx.x;
  if (i < 65536) {
    const int b = i >> 14, h = (i >> 10) & 15, s = i & 1023;
    const unsigned short* kr = kb + ((size_t)(s * 4 + b)) * 1024 + h * 64;
    const float* ur = pbu + h * 64;
    float sum = 0.f;
#pragma unroll
    for (int c = 0; c < 8; ++c) {
      short8 kv = *(const short8*)(kr + c * 8);
#pragma unroll
      for (int e = 0; e < 8; ++e) sum += bf2f((unsigned short)kv[e]) * ur[c * 8 + e];
    }
    uk[i] = sum;
  } else if (i < 98304) {
    const int j = i - 65536;
    const int idx = j >> 4, h = j & 15;
    const unsigned short* pr = pb + (size_t)idx * 1024 + h * 64;
    const float* vr = pbv + h * 64;
    float sum = 0.f;
#pragma unroll
    for (int c = 0; c < 8; ++c) {
      short8 pv = *(const short8*)(pr + c * 8);
#pragma unroll
      for (int e = 0; e < 8; ++e) sum += bf2f((unsigned short)pv[e]) * vr[c * 8 + e];
    }
    vp[(idx << 4) + h] = sum;
  }
}

// ---------------------------------------------------------------------------
// Fused rel-pos MFMA attention (flash-style, transposed scores). Unchanged R3.
// ---------------------------------------------------------------------------
__global__ __launch_bounds__(256) void attn_kernel(
    const unsigned short* __restrict__ qb, const unsigned short* __restrict__ kb,
    const unsigned short* __restrict__ pb, const unsigned short* __restrict__ vT,
    const float* __restrict__ uk, const float* __restrict__ vp,
    unsigned short* __restrict__ xb)
{
  __shared__ __align__(16) unsigned short Pb[64 * 136];  // P[t][s] bf16
  __shared__ __align__(16) float BDf[64 * 196];          // BD[t][jj] fp32
  __shared__ float uk_s[128], vp_w[192];
  __shared__ float pmax[2][64], psum[2][64];
  __shared__ float m_row[64], l_row[64], alpha_row[64];

  const int tid = threadIdx.x;
  const int lane = tid & 63;
  const int w = tid >> 6;
  const int l15 = lane & 15, quad = lane >> 4;
  const int th = w & 1, sh = w >> 1;

  const int flat = blockIdx.x + (blockIdx.y << 4) + (blockIdx.z << 8);
  const int x8 = flat & 7, s8 = flat >> 3;
  const int hb = x8 * 8 + (s8 >> 4);
  const int t0 = (s8 & 15) * 64;
  const int b = hb >> 4, h = hb & 15;

  short8 qf[2][2];
#pragma unroll
  for (int tt = 0; tt < 2; ++tt)
#pragma unroll
    for (int kk = 0; kk < 2; ++kk) {
      const int t = t0 + th * 32 + tt * 16 + l15;
      qf[tt][kk] = *(const short8*)(qb + ((size_t)(t * 4 + b)) * 1024 + h * 64 + kk * 32 + quad * 8);
    }

  floatx4 of[2][2];
#pragma unroll
  for (int i = 0; i < 2; ++i)
#pragma unroll
    for (int j = 0; j < 2; ++j) of[i][j] = (floatx4){0.f, 0.f, 0.f, 0.f};

  if (tid < 64) { m_row[tid] = -3.0e38f; l_row[tid] = 0.f; }
  __syncthreads();

  for (int s0 = 0; s0 < 1024; s0 += 128) {
    const int w0 = s0 - t0 + 960;

    if (tid < 128) uk_s[tid] = uk[((b * 16 + h) << 10) + s0 + tid];
    if (tid < 192) vp_w[tid] = vp[(((size_t)(w0 + tid)) << 4) + h];

    {
      floatx4 bd[6][2];
#pragma unroll
      for (int jt = 0; jt < 6; ++jt) {
        const int jj = sh * 96 + jt * 16 + l15;
        const unsigned short* pr = pb + ((size_t)(w0 + jj)) * 1024 + h * 64;
        short8 pf0 = *(const short8*)(pr + quad * 8);
        short8 pf1 = *(const short8*)(pr + 32 + quad * 8);
#pragma unroll
        for (int tt = 0; tt < 2; ++tt) {
          floatx4 z = (floatx4){0.f, 0.f, 0.f, 0.f};
          z = MFMA(pf0, qf[tt][0], z);
          z = MFMA(pf1, qf[tt][1], z);
          bd[jt][tt] = z;
        }
      }
#pragma unroll
      for (int jt = 0; jt < 6; ++jt)
#pragma unroll
        for (int tt = 0; tt < 2; ++tt) {
          const int tloc = th * 32 + tt * 16 + l15;
          const int jjb = sh * 96 + jt * 16 + quad * 4;
          *(float4*)&BDf[tloc * 196 + jjb] =
              make_float4(bd[jt][tt][0], bd[jt][tt][1], bd[jt][tt][2], bd[jt][tt][3]);
        }
    }

    floatx4 st[4][2];
#pragma unroll
    for (int stile = 0; stile < 4; ++stile) {
      const int srow = s0 + sh * 64 + stile * 16 + l15;
      const unsigned short* kr = kb + ((size_t)(srow * 4 + b)) * 1024 + h * 64;
      short8 kf0 = *(const short8*)(kr + quad * 8);
      short8 kf1 = *(const short8*)(kr + 32 + quad * 8);
#pragma unroll
      for (int tt = 0; tt < 2; ++tt) {
        floatx4 z = (floatx4){0.f, 0.f, 0.f, 0.f};
        z = MFMA(kf0, qf[tt][0], z);
        z = MFMA(kf1, qf[tt][1], z);
        st[stile][tt] = z;
      }
    }
    __syncthreads();  // B_a

    float lmax[2] = {-3.0e38f, -3.0e38f};
#pragma unroll
    for (int stile = 0; stile < 4; ++stile)
#pragma unroll
      for (int tt = 0; tt < 2; ++tt) {
        const int tloc = th * 32 + tt * 16 + l15;
#pragma unroll
        for (int reg = 0; reg < 4; ++reg) {
          const int sloc = sh * 64 + stile * 16 + quad * 4 + reg;
          const int jj = sloc - tloc + 63;
          float v = 0.125f * (st[stile][tt][reg] + BDf[tloc * 196 + jj] +
                              uk_s[sloc] + vp_w[jj]);
          st[stile][tt][reg] = v;
          lmax[tt] = fmaxf(lmax[tt], v);
        }
      }
#pragma unroll
    for (int tt = 0; tt < 2; ++tt) {
      lmax[tt] = fmaxf(lmax[tt], __shfl_xor(lmax[tt], 16));
      lmax[tt] = fmaxf(lmax[tt], __shfl_xor(lmax[tt], 32));
    }
    if (quad == 0) {
      pmax[sh][th * 32 + l15] = lmax[0];
      pmax[sh][th * 32 + 16 + l15] = lmax[1];
    }
    __syncthreads();  // B_b

    if (tid < 64) {
      const float mo = m_row[tid];
      const float mn = fmaxf(mo, fmaxf(pmax[0][tid], pmax[1][tid]));
      alpha_row[tid] = __expf(mo - mn);
      m_row[tid] = mn;
    }
    __syncthreads();  // B_c

    float lsum[2] = {0.f, 0.f};
    float mt[2];
#pragma unroll
    for (int tt = 0; tt < 2; ++tt) mt[tt] = m_row[th * 32 + tt * 16 + l15];
#pragma unroll
    for (int stile = 0; stile < 4; ++stile)
#pragma unroll
      for (int tt = 0; tt < 2; ++tt) {
        float p0 = __expf(st[stile][tt][0] - mt[tt]);
        float p1 = __expf(st[stile][tt][1] - mt[tt]);
        float p2 = __expf(st[stile][tt][2] - mt[tt]);
        float p3 = __expf(st[stile][tt][3] - mt[tt]);
        lsum[tt] += p0 + p1 + p2 + p3;
        const int tloc = th * 32 + tt * 16 + l15;
        const int sb = sh * 64 + stile * 16 + quad * 4;
        ushort4v pk = (ushort4v){f2bf(p0), f2bf(p1), f2bf(p2), f2bf(p3)};
        *(ushort4v*)&Pb[tloc * 136 + sb] = pk;
      }
#pragma unroll
    for (int tt = 0; tt < 2; ++tt) {
      lsum[tt] += __shfl_xor(lsum[tt], 16);
      lsum[tt] += __shfl_xor(lsum[tt], 32);
    }
    if (quad == 0) {
      psum[sh][th * 32 + l15] = lsum[0];
      psum[sh][th * 32 + 16 + l15] = lsum[1];
    }
#pragma unroll
    for (int tt = 0; tt < 2; ++tt)
#pragma unroll
      for (int reg = 0; reg < 4; ++reg) {
        const float ar = alpha_row[th * 32 + tt * 16 + quad * 4 + reg];
        of[tt][0][reg] *= ar;
        of[tt][1][reg] *= ar;
      }
    __syncthreads();  // B_d

    if (tid < 64)
      l_row[tid] = l_row[tid] * alpha_row[tid] + psum[0][tid] + psum[1][tid];
#pragma unroll
    for (int kk2 = 0; kk2 < 4; ++kk2) {
      short8 pa[2], vf[2];
#pragma unroll
      for (int tt = 0; tt < 2; ++tt)
        pa[tt] = *(short8*)&Pb[(th * 32 + tt * 16 + l15) * 136 + kk2 * 32 + quad * 8];
#pragma unroll
      for (int dt = 0; dt < 2; ++dt)
        vf[dt] = *(const short8*)(vT + ((size_t)((b * 16 + h) * 64 + sh * 32 + dt * 16 + l15)) * 1024 +
                                  s0 + kk2 * 32 + quad * 8);
#pragma unroll
      for (int tt = 0; tt < 2; ++tt)
#pragma unroll
        for (int dt = 0; dt < 2; ++dt)
          of[tt][dt] = MFMA(pa[tt], vf[dt], of[tt][dt]);
    }
  }
  __syncthreads();

#pragma unroll
  for (int tt = 0; tt < 2; ++tt)
#pragma unroll
    for (int reg = 0; reg < 4; ++reg) {
      const int t = th * 32 + tt * 16 + quad * 4 + reg;
      const float il = 1.f / l_row[t];
#pragma unroll
      for (int dt = 0; dt < 2; ++dt) {
        const int d = sh * 32 + dt * 16 + l15;
        xb[((size_t)((t0 + t) * 4 + b)) * 1024 + h * 64 + d] = f2bf(of[tt][dt][reg] * il);
      }
    }
}

// ---------------------------------------------------------------------------
extern "C" void kernel_launch(void* const* d_in, const int* in_sizes, int n_in,
                              void* d_out, int out_size, void* d_ws, size_t ws_size,
                              hipStream_t stream) {
  const float* query   = (const float*)d_in[0];
  const float* key_    = (const float*)d_in[1];
  const float* value   = (const float*)d_in[2];
  const float* pos_emb = (const float*)d_in[3];
  const float* Wq  = (const float*)d_in[4];
  const float* bq  = (const float*)d_in[5];
  const float* Wk  = (const float*)d_in[6];
  const float* bk  = (const float*)d_in[7];
  const float* Wv  = (const float*)d_in[8];
  const float* bv  = (const float*)d_in[9];
  const float* Wp  = (const float*)d_in[10];
  const float* Wo  = (const float*)d_in[11];
  const float* bo  = (const float*)d_in[12];
  const float* pbu = (const float*)d_in[13];
  const float* pbv = (const float*)d_in[14];
  float* out = (float*)d_out;

  // workspace (ushort elements), ~69.6 MB total
  unsigned short* U = (unsigned short*)d_ws;
  unsigned short* qin = U;                   // 4096x1024 bf16 query  (later: attn out)
  unsigned short* kin = U + 4194304;         // 4096x1024 bf16 key    (later: v-proj out)
  unsigned short* vin = U + 8388608;         // 4096x1024 bf16 value
  unsigned short* pe  = U + 12582912;        // 2048x1024 bf16 pos_emb (row 2047 zero)
  unsigned short* wq  = U + 14680064;        // 1024x1024 each
  unsigned short* wk  = U + 15728640;
  unsigned short* wv  = U + 16777216;
  unsigned short* wp  = U + 17825792;
  unsigned short* wo  = U + 18874368;
  unsigned short* qb  = U + 19922944;        // Q proj 4096x1024
  unsigned short* kb  = U + 24117248;        // K proj
  unsigned short* pb  = U + 28311552;        // P proj 2048x1024
  unsigned short* vTb = U + 30408704;        // [b][h][64][1024]
  unsigned short* vpo = kin;                 // V proj out (kin dead after QKP GEMM)
  unsigned short* xb  = qin;                 // attn out (qin dead after QKP GEMM)
  float* fbase = (float*)(U + 34603008);
  float* uk = fbase;                         // 65536 floats
  float* vp = fbase + 65536;                 // 32768 floats

  const dim3 blk(256);

  // 1. convert everything to bf16 (one HBM-bound pass)
  convert_kernel<<<dim3(9728), blk, 0, stream>>>(
      query, key_, value, pos_emb, Wq, Wk, Wv, Wp, Wo,
      qin, kin, vin, pe, wq, wk, wv, wp, wo);

  // 2. fused Q,K,P projections (640 active blocks)
  GemmJobs jobs;
  jobs.j[0] = GemmJob{qin, wq, bq, qb, 32};
  jobs.j[1] = GemmJob{kin, wk, bk, kb, 32};
  jobs.j[2] = GemmJob{pe,  wp, nullptr, pb, 16};
  gemm_qkp<<<dim3(8, 32, 3), blk, 0, stream>>>(jobs);

  // 3. V projection (writes into dead kin buffer)
  gemm_one<1><<<dim3(8, 32), blk, 0, stream>>>(vin, wv, bv, vpo);

  // 4. transpose V for PV MFMA B-operand
  transpose_v<<<dim3(8, 16, 4), blk, 0, stream>>>(vpo, vTb);

  // 5. rank-1 bias dots
  precompute_kernel<<<dim3(384), blk, 0, stream>>>(kb, pb, pbu, pbv, uk, vp);

  // 6. fused attention (writes into dead qin buffer)
  attn_kernel<<<dim3(16, 16, 4), blk, 0, stream>>>(qb, kb, pb, vTb, uk, vp, xb);

  // 7. output projection -> fp32 d_out
  gemm_one<0><<<dim3(8, 32), blk, 0, stream>>>(xb, wo, bo, out);
}